// Round 1
// baseline (174.189 us; speedup 1.0000x reference)
//
#include <hip/hip_runtime.h>

#define NPTS 262144
#define RES  256
#define PD   32

typedef unsigned short u16;
typedef unsigned int   u32;

typedef __bf16 bf16x8 __attribute__((ext_vector_type(8)));
typedef float  f32x4  __attribute__((ext_vector_type(4)));

__device__ __forceinline__ u16 f2bf(float f) {
    return __builtin_bit_cast(u16, (__bf16)f);
}
__device__ __forceinline__ float bf2f(u32 u) {
    return __builtin_bit_cast(float, (u32)(u << 16));
}

// ---------------------------------------------------------------------------
// Prep 1: triplanes (3,32,256,256) fp32 -> (3,256,256,32) bf16
// grid = 3*256 blocks, 256 threads (x)
// ---------------------------------------------------------------------------
__global__ void k_transpose_planes(const float* __restrict__ tp, u16* __restrict__ dst) {
    const int b  = blockIdx.x;          // 0..767
    const int pl = b >> 8, y = b & 255;
    const int x  = threadIdx.x;         // 0..255
    const float* src = tp + ((size_t)pl * PD * RES + y) * RES + x;   // + c*65536
    u32 w[16];
#pragma unroll
    for (int c = 0; c < 16; ++c) {
        const float v0 = src[(size_t)(2 * c)     * (RES * RES)];
        const float v1 = src[(size_t)(2 * c + 1) * (RES * RES)];
        w[c] = (u32)f2bf(v0) | ((u32)f2bf(v1) << 16);
    }
    uint4* d = (uint4*)(dst + (size_t)((pl * RES + y) * RES + x) * PD);
    d[0] = make_uint4(w[0],  w[1],  w[2],  w[3]);
    d[1] = make_uint4(w[4],  w[5],  w[6],  w[7]);
    d[2] = make_uint4(w[8],  w[9],  w[10], w[11]);
    d[3] = make_uint4(w[12], w[13], w[14], w[15]);
}

// ---------------------------------------------------------------------------
// Prep 2: weights -> bf16, transposed to (N x K) row-major.
//   w1d: 128 x 32   (density W1^T)
//   w1c: 128 x 64   (color   W1^T, k>=59 zero)
//   w2d: 128 x 128  w2c: 128 x 128
// grid = 64 blocks x 256 threads = 16384 = 128*128
// ---------------------------------------------------------------------------
__global__ void k_prep_weights(const float* __restrict__ dW1, const float* __restrict__ dW2,
                               const float* __restrict__ cW1, const float* __restrict__ cW2,
                               u16* __restrict__ w1d, u16* __restrict__ w1c,
                               u16* __restrict__ w2d, u16* __restrict__ w2c) {
    const int tid = blockIdx.x * 256 + threadIdx.x;   // 0..16383
    if (tid < 128 * 32) { const int n = tid >> 5, k = tid & 31; w1d[tid] = f2bf(dW1[k * 128 + n]); }
    if (tid < 128 * 64) { const int n = tid >> 6, k = tid & 63; w1c[tid] = f2bf(k < 59 ? cW1[k * 128 + n] : 0.f); }
    { const int n = tid >> 7, k = tid & 127;
      w2d[tid] = f2bf(dW2[k * 128 + n]);
      w2c[tid] = f2bf(cW2[k * 128 + n]); }
}

// ---------------------------------------------------------------------------
// Fused head kernel. 2048 blocks x 512 threads, TILE = 128 points/block.
// ---------------------------------------------------------------------------
__global__ __launch_bounds__(512, 2) void k_fused(
    const float* __restrict__ pts, const float* __restrict__ vds,
    const u16* __restrict__ planes,
    const u16* __restrict__ gW1d, const u16* __restrict__ gW1c,
    const u16* __restrict__ gW2d, const u16* __restrict__ gW2c,
    const float* __restrict__ gB1d, const float* __restrict__ gB2d,
    const float* __restrict__ gW3d, const float* __restrict__ gB3d,
    const float* __restrict__ gB1c, const float* __restrict__ gB2c,
    const float* __restrict__ gW3c, const float* __restrict__ gB3c,
    float* __restrict__ out) {
    // ---- LDS (all 16B-aligned; all 2D tiles XOR-swizzled by row) ----
    __shared__ __align__(16) u16 sW1d[128 * 32];    //  8 KB, 64B rows  (mask 3)
    __shared__ __align__(16) u16 sW1c[128 * 64];    // 16 KB, 128B rows (mask 7)
    __shared__ __align__(16) u16 sW2d[128 * 128];   // 32 KB, 256B rows (mask 7)
    __shared__ __align__(16) u16 sW2c[128 * 128];   // 32 KB
    __shared__ __align__(16) u16 sX[128 * 64];      // 16 KB, 128B rows (mask 7)
    __shared__ __align__(16) u16 sH[128 * 128];     // 32 KB, 256B rows (mask 7)
    __shared__ float sB1d[128], sB2d[128], sB1c[128], sB2c[128];
    __shared__ float sW3d[128], sW3c[3 * 128];
    __shared__ float sAcc[4 * 128];

    const int t    = threadIdx.x;
    const int lane = t & 63;
    const int wid  = t >> 6;
    const int l15  = lane & 15;
    const int l4   = lane >> 4;
    const int pbase = blockIdx.x * 128;

    // ---- stage weights into LDS (swizzled) ----
    {
        const uint4* s = (const uint4*)gW1d;
        for (int u = t; u < 128 * 32 / 8; u += 512) {
            const int r = u >> 2, c = (u & 3) * 16;
            *(uint4*)((char*)sW1d + r * 64 + (c ^ ((r & 3) << 4))) = s[u];
        }
        s = (const uint4*)gW1c;
        for (int u = t; u < 128 * 64 / 8; u += 512) {
            const int r = u >> 3, c = (u & 7) * 16;
            *(uint4*)((char*)sW1c + r * 128 + (c ^ ((r & 7) << 4))) = s[u];
        }
        s = (const uint4*)gW2d;
        for (int u = t; u < 128 * 128 / 8; u += 512) {
            const int r = u >> 4, c = (u & 15) * 16;
            *(uint4*)((char*)sW2d + r * 256 + (c ^ ((r & 7) << 4))) = s[u];
        }
        s = (const uint4*)gW2c;
        for (int u = t; u < 128 * 128 / 8; u += 512) {
            const int r = u >> 4, c = (u & 15) * 16;
            *(uint4*)((char*)sW2c + r * 256 + (c ^ ((r & 7) << 4))) = s[u];
        }
        if (t < 128) {
            sB1d[t] = gB1d[t]; sB2d[t] = gB2d[t];
            sB1c[t] = gB1c[t]; sB2c[t] = gB2c[t];
            sW3d[t] = gW3d[t];
            sW3c[0 * 128 + t] = gW3c[t * 3 + 0];
            sW3c[1 * 128 + t] = gW3c[t * 3 + 1];
            sW3c[2 * 128 + t] = gW3c[t * 3 + 2];
            sAcc[t] = 0.f; sAcc[128 + t] = 0.f; sAcc[256 + t] = 0.f; sAcc[384 + t] = 0.f;
        }
    }

    // ---- phase 1: bilinear triplane sampling + view embedding -> sX ----
    {
        const int p = t >> 2, q = t & 3;       // 4 threads/point, q = 8-channel slice
        const int pg = pbase + p;
        const float pu = pts[pg], pv = pts[NPTS + pg], pw = pts[2 * NPTS + pg];
        float facc[8] = {0.f, 0.f, 0.f, 0.f, 0.f, 0.f, 0.f, 0.f};
#pragma unroll
        for (int pl = 0; pl < 3; ++pl) {
            // plane_x: (gx=v, gy=w); plane_y: (gx=u, gy=w); plane_z: (gx=u, gy=v)
            const float gx = (pl == 0) ? pv : pu;
            const float gy = (pl == 2) ? pv : pw;
            const float px = (gx + 1.f) * 127.5f;
            const float py = (gy + 1.f) * 127.5f;
            const float x0 = floorf(px), y0 = floorf(py);
            const float fx = px - x0, fy = py - y0;
            const int ix = (int)x0, iy = (int)y0;
            const u16* pb = planes + (size_t)pl * (RES * RES * PD) + q * 8;
#pragma unroll
            for (int dy = 0; dy < 2; ++dy) {
#pragma unroll
                for (int dx = 0; dx < 2; ++dx) {
                    const int xi = ix + dx, yi = iy + dy;
                    float wt = (dx ? fx : 1.f - fx) * (dy ? fy : 1.f - fy);
                    if (xi < 0 || xi > RES - 1 || yi < 0 || yi > RES - 1) wt = 0.f;
                    const int xc = xi < 0 ? 0 : (xi > RES - 1 ? RES - 1 : xi);
                    const int yc = yi < 0 ? 0 : (yi > RES - 1 ? RES - 1 : yi);
                    const uint4 v = *(const uint4*)(pb + ((size_t)(yc * RES + xc) << 5));
                    facc[0] += wt * bf2f(v.x & 0xffffu);
                    facc[1] += wt * bf2f(v.x >> 16);
                    facc[2] += wt * bf2f(v.y & 0xffffu);
                    facc[3] += wt * bf2f(v.y >> 16);
                    facc[4] += wt * bf2f(v.z & 0xffffu);
                    facc[5] += wt * bf2f(v.z >> 16);
                    facc[6] += wt * bf2f(v.w & 0xffffu);
                    facc[7] += wt * bf2f(v.w >> 16);
                }
            }
        }
        u32 wp[4];
#pragma unroll
        for (int i = 0; i < 4; ++i)
            wp[i] = (u32)f2bf(facc[2 * i]) | ((u32)f2bf(facc[2 * i + 1]) << 16);
        *(uint4*)((char*)sX + p * 128 + ((q * 16) ^ ((p & 7) << 4))) =
            make_uint4(wp[0], wp[1], wp[2], wp[3]);

        if (q == 0) {   // view embedding -> X cols 32..63 (59..63 zero-padded)
            const float d0 = vds[pg], d1 = vds[NPTS + pg], d2 = vds[2 * NPTS + pg];
            float e[32];
            e[0] = d0; e[1] = d1; e[2] = d2;
#pragma unroll
            for (int f = 0; f < 4; ++f) {
                const float fr = (float)(1 << f);
                e[3  + f * 3 + 0] = __sinf(d0 * fr);
                e[3  + f * 3 + 1] = __sinf(d1 * fr);
                e[3  + f * 3 + 2] = __sinf(d2 * fr);
                e[15 + f * 3 + 0] = __cosf(d0 * fr);
                e[15 + f * 3 + 1] = __cosf(d1 * fr);
                e[15 + f * 3 + 2] = __cosf(d2 * fr);
            }
#pragma unroll
            for (int i = 27; i < 32; ++i) e[i] = 0.f;
#pragma unroll
            for (int i = 0; i < 4; ++i) {
                const u32 a0 = (u32)f2bf(e[8 * i + 0]) | ((u32)f2bf(e[8 * i + 1]) << 16);
                const u32 a1 = (u32)f2bf(e[8 * i + 2]) | ((u32)f2bf(e[8 * i + 3]) << 16);
                const u32 a2 = (u32)f2bf(e[8 * i + 4]) | ((u32)f2bf(e[8 * i + 5]) << 16);
                const u32 a3 = (u32)f2bf(e[8 * i + 6]) | ((u32)f2bf(e[8 * i + 7]) << 16);
                *(uint4*)((char*)sX + p * 128 + ((64 + i * 16) ^ ((p & 7) << 4))) =
                    make_uint4(a0, a1, a2, a3);
            }
        }
    }
    __syncthreads();

    // ---- GEMM phase: wave grid 2 (M) x 4 (N); wave owns 64 rows x 32 cols ----
    const int wr = wid >> 2;        // 0..1
    const int wc = wid & 3;         // 0..3
    const int kb = l4 * 16;         // byte offset of lane's k-slice inside a 64B k-step
    const f32x4 FZ = {0.f, 0.f, 0.f, 0.f};

    // X a-fragments, cached for both chains' GEMM1
    bf16x8 aX[4][2];
#pragma unroll
    for (int mt = 0; mt < 4; ++mt) {
        const int m = wr * 64 + mt * 16 + l15;
        const int sw = (m & 7) << 4;
        aX[mt][0] = *(const bf16x8*)((const char*)sX + m * 128 + ((0 * 64 + kb) ^ sw));
        aX[mt][1] = *(const bf16x8*)((const char*)sX + m * 128 + ((1 * 64 + kb) ^ sw));
    }

    // ================= DENSITY: GEMM1 (K=32) =================
    {
        f32x4 acc1[4][2];
#pragma unroll
        for (int mt = 0; mt < 4; ++mt)
#pragma unroll
            for (int nl = 0; nl < 2; ++nl) acc1[mt][nl] = FZ;
#pragma unroll
        for (int nl = 0; nl < 2; ++nl) {
            const int n = wc * 32 + nl * 16 + l15;
            const bf16x8 b = *(const bf16x8*)((const char*)sW1d + n * 64 + (kb ^ ((n & 3) << 4)));
#pragma unroll
            for (int mt = 0; mt < 4; ++mt)
                acc1[mt][nl] = __builtin_amdgcn_mfma_f32_16x16x32_bf16(aX[mt][0], b, acc1[mt][nl], 0, 0, 0);
        }
#pragma unroll
        for (int mt = 0; mt < 4; ++mt)
#pragma unroll
            for (int nl = 0; nl < 2; ++nl) {
                const int n = wc * 32 + nl * 16 + l15;
                const float bias = sB1d[n];
#pragma unroll
                for (int r = 0; r < 4; ++r) {
                    const int m = wr * 64 + mt * 16 + l4 * 4 + r;
                    float h = acc1[mt][nl][r] + bias;
                    h = h > 0.f ? h : 0.f;
                    *(u16*)((char*)sH + m * 256 + ((n * 2) ^ ((m & 7) << 4))) = f2bf(h);
                }
            }
    }
    __syncthreads();

    // ================= DENSITY: GEMM2 (K=128) + final dot =================
    {
        f32x4 acc2[4][2];
#pragma unroll
        for (int mt = 0; mt < 4; ++mt)
#pragma unroll
            for (int nl = 0; nl < 2; ++nl) acc2[mt][nl] = FZ;
#pragma unroll
        for (int kk = 0; kk < 4; ++kk) {
            bf16x8 a[4];
#pragma unroll
            for (int mt = 0; mt < 4; ++mt) {
                const int m = wr * 64 + mt * 16 + l15;
                a[mt] = *(const bf16x8*)((const char*)sH + m * 256 + ((kk * 64 + kb) ^ ((m & 7) << 4)));
            }
#pragma unroll
            for (int nl = 0; nl < 2; ++nl) {
                const int n = wc * 32 + nl * 16 + l15;
                const bf16x8 b = *(const bf16x8*)((const char*)sW2d + n * 256 + ((kk * 64 + kb) ^ ((n & 7) << 4)));
#pragma unroll
                for (int mt = 0; mt < 4; ++mt)
                    acc2[mt][nl] = __builtin_amdgcn_mfma_f32_16x16x32_bf16(a[mt], b, acc2[mt][nl], 0, 0, 0);
            }
        }
        // h2 = relu(acc2 + b2d); density partial = sum_n h2 * w3d[n]
#pragma unroll
        for (int mt = 0; mt < 4; ++mt)
#pragma unroll
            for (int r = 0; r < 4; ++r) {
                float s = 0.f;
#pragma unroll
                for (int nl = 0; nl < 2; ++nl) {
                    const int n = wc * 32 + nl * 16 + l15;
                    float h = acc2[mt][nl][r] + sB2d[n];
                    h = h > 0.f ? h : 0.f;
                    s += h * sW3d[n];
                }
                s += __shfl_xor(s, 1);
                s += __shfl_xor(s, 2);
                s += __shfl_xor(s, 4);
                s += __shfl_xor(s, 8);
                if (l15 == 0)
                    atomicAdd(&sAcc[0 * 128 + wr * 64 + mt * 16 + l4 * 4 + r], s);
            }
    }
    __syncthreads();

    // ================= COLOR: GEMM1 (K=64) =================
    {
        f32x4 acc1[4][2];
#pragma unroll
        for (int mt = 0; mt < 4; ++mt)
#pragma unroll
            for (int nl = 0; nl < 2; ++nl) acc1[mt][nl] = FZ;
#pragma unroll
        for (int kk = 0; kk < 2; ++kk)
#pragma unroll
            for (int nl = 0; nl < 2; ++nl) {
                const int n = wc * 32 + nl * 16 + l15;
                const bf16x8 b = *(const bf16x8*)((const char*)sW1c + n * 128 + ((kk * 64 + kb) ^ ((n & 7) << 4)));
#pragma unroll
                for (int mt = 0; mt < 4; ++mt)
                    acc1[mt][nl] = __builtin_amdgcn_mfma_f32_16x16x32_bf16(aX[mt][kk], b, acc1[mt][nl], 0, 0, 0);
            }
#pragma unroll
        for (int mt = 0; mt < 4; ++mt)
#pragma unroll
            for (int nl = 0; nl < 2; ++nl) {
                const int n = wc * 32 + nl * 16 + l15;
                const float bias = sB1c[n];
#pragma unroll
                for (int r = 0; r < 4; ++r) {
                    const int m = wr * 64 + mt * 16 + l4 * 4 + r;
                    float h = acc1[mt][nl][r] + bias;
                    h = h > 0.f ? h : 0.f;
                    *(u16*)((char*)sH + m * 256 + ((n * 2) ^ ((m & 7) << 4))) = f2bf(h);
                }
            }
    }
    __syncthreads();

    // ================= COLOR: GEMM2 (K=128) + final dots =================
    {
        f32x4 acc2[4][2];
#pragma unroll
        for (int mt = 0; mt < 4; ++mt)
#pragma unroll
            for (int nl = 0; nl < 2; ++nl) acc2[mt][nl] = FZ;
#pragma unroll
        for (int kk = 0; kk < 4; ++kk) {
            bf16x8 a[4];
#pragma unroll
            for (int mt = 0; mt < 4; ++mt) {
                const int m = wr * 64 + mt * 16 + l15;
                a[mt] = *(const bf16x8*)((const char*)sH + m * 256 + ((kk * 64 + kb) ^ ((m & 7) << 4)));
            }
#pragma unroll
            for (int nl = 0; nl < 2; ++nl) {
                const int n = wc * 32 + nl * 16 + l15;
                const bf16x8 b = *(const bf16x8*)((const char*)sW2c + n * 256 + ((kk * 64 + kb) ^ ((n & 7) << 4)));
#pragma unroll
                for (int mt = 0; mt < 4; ++mt)
                    acc2[mt][nl] = __builtin_amdgcn_mfma_f32_16x16x32_bf16(a[mt], b, acc2[mt][nl], 0, 0, 0);
            }
        }
#pragma unroll
        for (int mt = 0; mt < 4; ++mt)
#pragma unroll
            for (int r = 0; r < 4; ++r) {
                float s0 = 0.f, s1 = 0.f, s2 = 0.f;
#pragma unroll
                for (int nl = 0; nl < 2; ++nl) {
                    const int n = wc * 32 + nl * 16 + l15;
                    float h = acc2[mt][nl][r] + sB2c[n];
                    h = h > 0.f ? h : 0.f;
                    s0 += h * sW3c[0 * 128 + n];
                    s1 += h * sW3c[1 * 128 + n];
                    s2 += h * sW3c[2 * 128 + n];
                }
                s0 += __shfl_xor(s0, 1); s0 += __shfl_xor(s0, 2); s0 += __shfl_xor(s0, 4); s0 += __shfl_xor(s0, 8);
                s1 += __shfl_xor(s1, 1); s1 += __shfl_xor(s1, 2); s1 += __shfl_xor(s1, 4); s1 += __shfl_xor(s1, 8);
                s2 += __shfl_xor(s2, 1); s2 += __shfl_xor(s2, 2); s2 += __shfl_xor(s2, 4); s2 += __shfl_xor(s2, 8);
                if (l15 == 0) {
                    const int m = wr * 64 + mt * 16 + l4 * 4 + r;
                    atomicAdd(&sAcc[1 * 128 + m], s0);
                    atomicAdd(&sAcc[2 * 128 + m], s1);
                    atomicAdd(&sAcc[3 * 128 + m], s2);
                }
            }
    }
    __syncthreads();

    // ---- write out (1,4,N): ch0 = density, ch1..3 = color ----
    {
        const int ch = t >> 7, row = t & 127;
        const float bias = (ch == 0) ? gB3d[0] : gB3c[ch - 1];
        out[(size_t)ch * NPTS + pbase + row] = sAcc[ch * 128 + row] + bias;
    }
}

// ---------------------------------------------------------------------------
extern "C" void kernel_launch(void* const* d_in, const int* in_sizes, int n_in,
                              void* d_out, int out_size, void* d_ws, size_t ws_size,
                              hipStream_t stream) {
    (void)in_sizes; (void)n_in; (void)out_size; (void)ws_size;
    const float* pts = (const float*)d_in[0];
    const float* vds = (const float*)d_in[1];
    const float* tp  = (const float*)d_in[2];
    const float* dW1 = (const float*)d_in[3];
    const float* dB1 = (const float*)d_in[4];
    const float* dW2 = (const float*)d_in[5];
    const float* dB2 = (const float*)d_in[6];
    const float* dW3 = (const float*)d_in[7];
    const float* dB3 = (const float*)d_in[8];
    const float* cW1 = (const float*)d_in[9];
    const float* cB1 = (const float*)d_in[10];
    const float* cW2 = (const float*)d_in[11];
    const float* cB2 = (const float*)d_in[12];
    const float* cW3 = (const float*)d_in[13];
    const float* cB3 = (const float*)d_in[14];
    float* out = (float*)d_out;

    u16* planes_t = (u16*)d_ws;                          // 3*256*256*32 bf16 = 12 MB
    u16* w1d = planes_t + (size_t)3 * RES * RES * PD;
    u16* w1c = w1d + 128 * 32;
    u16* w2d = w1c + 128 * 64;
    u16* w2c = w2d + 128 * 128;

    k_transpose_planes<<<3 * RES, 256, 0, stream>>>(tp, planes_t);
    k_prep_weights<<<64, 256, 0, stream>>>(dW1, dW2, cW1, cW2, w1d, w1c, w2d, w2c);
    k_fused<<<NPTS / 128, 512, 0, stream>>>(pts, vds, planes_t,
                                            w1d, w1c, w2d, w2c,
                                            dB1, dB2, dW3, dB3,
                                            cB1, cB2, cW3, cB3,
                                            out);
}

// Round 2
// 167.153 us; speedup vs baseline: 1.0421x; 1.0421x over previous
//
#include <hip/hip_runtime.h>

#define NPTS 262144
#define RES  256
#define PD   32

typedef unsigned short u16;
typedef unsigned int   u32;

typedef __bf16 bf16x8 __attribute__((ext_vector_type(8)));
typedef float  f32x4  __attribute__((ext_vector_type(4)));

__device__ __forceinline__ u16 f2bf(float f) {
    return __builtin_bit_cast(u16, (__bf16)f);
}
__device__ __forceinline__ float bf2f(u32 u) {
    return __builtin_bit_cast(float, (u32)(u << 16));
}

// ---------------------------------------------------------------------------
// Prep 1: triplanes (3,32,256,256) fp32 -> (3,256,256,32) bf16
// ---------------------------------------------------------------------------
__global__ void k_transpose_planes(const float* __restrict__ tp, u16* __restrict__ dst) {
    const int b  = blockIdx.x;          // 0..767
    const int pl = b >> 8, y = b & 255;
    const int x  = threadIdx.x;         // 0..255
    const float* src = tp + ((size_t)pl * PD * RES + y) * RES + x;
    u32 w[16];
#pragma unroll
    for (int c = 0; c < 16; ++c) {
        const float v0 = src[(size_t)(2 * c)     * (RES * RES)];
        const float v1 = src[(size_t)(2 * c + 1) * (RES * RES)];
        w[c] = (u32)f2bf(v0) | ((u32)f2bf(v1) << 16);
    }
    uint4* d = (uint4*)(dst + (size_t)((pl * RES + y) * RES + x) * PD);
    d[0] = make_uint4(w[0],  w[1],  w[2],  w[3]);
    d[1] = make_uint4(w[4],  w[5],  w[6],  w[7]);
    d[2] = make_uint4(w[8],  w[9],  w[10], w[11]);
    d[3] = make_uint4(w[12], w[13], w[14], w[15]);
}

// ---------------------------------------------------------------------------
// Prep 2: weights -> bf16, transposed to (N x K) row-major.
// ---------------------------------------------------------------------------
__global__ void k_prep_weights(const float* __restrict__ dW1, const float* __restrict__ dW2,
                               const float* __restrict__ cW1, const float* __restrict__ cW2,
                               u16* __restrict__ w1d, u16* __restrict__ w1c,
                               u16* __restrict__ w2d, u16* __restrict__ w2c) {
    const int tid = blockIdx.x * 256 + threadIdx.x;   // 0..16383
    if (tid < 128 * 32) { const int n = tid >> 5, k = tid & 31; w1d[tid] = f2bf(dW1[k * 128 + n]); }
    if (tid < 128 * 64) { const int n = tid >> 6, k = tid & 63; w1c[tid] = f2bf(k < 59 ? cW1[k * 128 + n] : 0.f); }
    { const int n = tid >> 7, k = tid & 127;
      w2d[tid] = f2bf(dW2[k * 128 + n]);
      w2c[tid] = f2bf(cW2[k * 128 + n]); }
}

// ---------------------------------------------------------------------------
// Fused head kernel. 2048 blocks x 512 threads, TILE = 128 points/block.
// LDS = 50 KB -> 3 blocks/CU; weights read directly from global (L2-hot).
// ---------------------------------------------------------------------------
__global__ __launch_bounds__(512, 6) void k_fused(
    const float* __restrict__ pts, const float* __restrict__ vds,
    const u16* __restrict__ planes,
    const u16* __restrict__ gW1d, const u16* __restrict__ gW1c,
    const u16* __restrict__ gW2d, const u16* __restrict__ gW2c,
    const float* __restrict__ gB1d, const float* __restrict__ gB2d,
    const float* __restrict__ gW3d, const float* __restrict__ gB3d,
    const float* __restrict__ gB1c, const float* __restrict__ gB2c,
    const float* __restrict__ gW3c, const float* __restrict__ gB3c,
    float* __restrict__ out) {
    __shared__ __align__(16) u16 sX[128 * 64];      // 16 KB, 128B rows, XOR-swizzled
    __shared__ __align__(16) u16 sH[128 * 128];     // 32 KB, 256B rows, XOR-swizzled
    __shared__ float sAcc[4 * 128];                 //  2 KB

    const int t    = threadIdx.x;
    const int lane = t & 63;
    const int wid  = t >> 6;
    const int l15  = lane & 15;
    const int l4   = lane >> 4;
    const int pbase = blockIdx.x * 128;

    sAcc[t & 511] = 0.f;   // 512 threads cover all 512 slots

    // ---- phase 1: bilinear triplane sampling + view embedding -> sX ----
    {
        const int p = t >> 2, q = t & 3;       // 4 threads/point, q = 8-channel slice
        const int pg = pbase + p;
        const int sw = (p & 7) << 4;
        const float pu = pts[pg], pv = pts[NPTS + pg], pw = pts[2 * NPTS + pg];
        float facc[8] = {0.f, 0.f, 0.f, 0.f, 0.f, 0.f, 0.f, 0.f};
#pragma unroll
        for (int pl = 0; pl < 3; ++pl) {
            const float gx = (pl == 0) ? pv : pu;
            const float gy = (pl == 2) ? pv : pw;
            const float px = (gx + 1.f) * 127.5f;
            const float py = (gy + 1.f) * 127.5f;
            const float x0 = floorf(px), y0 = floorf(py);
            const float fx = px - x0, fy = py - y0;
            const int ix = (int)x0, iy = (int)y0;
            const u16* pb = planes + (size_t)pl * (RES * RES * PD) + q * 8;
#pragma unroll
            for (int dy = 0; dy < 2; ++dy) {
#pragma unroll
                for (int dx = 0; dx < 2; ++dx) {
                    const int xi = ix + dx, yi = iy + dy;
                    float wt = (dx ? fx : 1.f - fx) * (dy ? fy : 1.f - fy);
                    if (xi < 0 || xi > RES - 1 || yi < 0 || yi > RES - 1) wt = 0.f;
                    const int xc = xi < 0 ? 0 : (xi > RES - 1 ? RES - 1 : xi);
                    const int yc = yi < 0 ? 0 : (yi > RES - 1 ? RES - 1 : yi);
                    const uint4 v = *(const uint4*)(pb + ((size_t)(yc * RES + xc) << 5));
                    facc[0] += wt * bf2f(v.x & 0xffffu);
                    facc[1] += wt * bf2f(v.x >> 16);
                    facc[2] += wt * bf2f(v.y & 0xffffu);
                    facc[3] += wt * bf2f(v.y >> 16);
                    facc[4] += wt * bf2f(v.z & 0xffffu);
                    facc[5] += wt * bf2f(v.z >> 16);
                    facc[6] += wt * bf2f(v.w & 0xffffu);
                    facc[7] += wt * bf2f(v.w >> 16);
                }
            }
        }
        {
            u32 wp[4];
#pragma unroll
            for (int i = 0; i < 4; ++i)
                wp[i] = (u32)f2bf(facc[2 * i]) | ((u32)f2bf(facc[2 * i + 1]) << 16);
            *(uint4*)((char*)sX + p * 128 + ((q * 16) ^ sw)) =
                make_uint4(wp[0], wp[1], wp[2], wp[3]);
        }

        // view embedding -> X cols 32..63 (59..63 zero): q==1 does [d|sin|cos(d0)],
        // q==2 does the remaining cos + pad. Spreads the trig across lanes.
        if (q == 1 || q == 2) {
            const float d0 = vds[pg], d1 = vds[NPTS + pg], d2 = vds[2 * NPTS + pg];
            float e[16];
            if (q == 1) {
                e[0] = d0; e[1] = d1; e[2] = d2;
#pragma unroll
                for (int f = 0; f < 4; ++f) {
                    const float fr = (float)(1 << f);
                    e[3 + f * 3 + 0] = __sinf(d0 * fr);
                    e[3 + f * 3 + 1] = __sinf(d1 * fr);
                    e[3 + f * 3 + 2] = __sinf(d2 * fr);
                }
                e[15] = __cosf(d0);
            } else {
                e[0] = __cosf(d1); e[1] = __cosf(d2);
#pragma unroll
                for (int f = 1; f < 4; ++f) {
                    const float fr = (float)(1 << f);
                    e[2 + (f - 1) * 3 + 0] = __cosf(d0 * fr);
                    e[2 + (f - 1) * 3 + 1] = __cosf(d1 * fr);
                    e[2 + (f - 1) * 3 + 2] = __cosf(d2 * fr);
                }
#pragma unroll
                for (int i = 11; i < 16; ++i) e[i] = 0.f;
            }
            const int base = 64 + (q - 1) * 32;
#pragma unroll
            for (int g = 0; g < 2; ++g) {
                const u32 a0 = (u32)f2bf(e[8 * g + 0]) | ((u32)f2bf(e[8 * g + 1]) << 16);
                const u32 a1 = (u32)f2bf(e[8 * g + 2]) | ((u32)f2bf(e[8 * g + 3]) << 16);
                const u32 a2 = (u32)f2bf(e[8 * g + 4]) | ((u32)f2bf(e[8 * g + 5]) << 16);
                const u32 a3 = (u32)f2bf(e[8 * g + 6]) | ((u32)f2bf(e[8 * g + 7]) << 16);
                *(uint4*)((char*)sX + p * 128 + ((base + g * 16) ^ sw)) =
                    make_uint4(a0, a1, a2, a3);
            }
        }
    }
    __syncthreads();

    // ---- GEMM phase: wave grid 2 (M) x 4 (N); wave owns 64 rows x 32 cols ----
    const int wr = wid >> 2;        // 0..1
    const int wc = wid & 3;         // 0..3
    const int kb = l4 * 16;         // byte offset of lane's k-slice in a 64B k-step
    const f32x4 FZ = {0.f, 0.f, 0.f, 0.f};

    // ================= DENSITY: GEMM1 (K=32) =================
    {
        f32x4 acc[4][2];
        bf16x8 a[4];
#pragma unroll
        for (int mt = 0; mt < 4; ++mt) {
            const int m = wr * 64 + mt * 16 + l15;
            a[mt] = *(const bf16x8*)((const char*)sX + m * 128 + (kb ^ ((m & 7) << 4)));
#pragma unroll
            for (int nl = 0; nl < 2; ++nl) acc[mt][nl] = FZ;
        }
#pragma unroll
        for (int nl = 0; nl < 2; ++nl) {
            const int n = wc * 32 + nl * 16 + l15;
            const bf16x8 b = *(const bf16x8*)(gW1d + n * 32 + l4 * 8);
#pragma unroll
            for (int mt = 0; mt < 4; ++mt)
                acc[mt][nl] = __builtin_amdgcn_mfma_f32_16x16x32_bf16(a[mt], b, acc[mt][nl], 0, 0, 0);
        }
#pragma unroll
        for (int nl = 0; nl < 2; ++nl) {
            const int n = wc * 32 + nl * 16 + l15;
            const float bias = gB1d[n];
#pragma unroll
            for (int mt = 0; mt < 4; ++mt)
#pragma unroll
                for (int r = 0; r < 4; ++r) {
                    const int m = wr * 64 + mt * 16 + l4 * 4 + r;
                    float h = acc[mt][nl][r] + bias;
                    h = h > 0.f ? h : 0.f;
                    *(u16*)((char*)sH + m * 256 + ((n * 2) ^ ((m & 7) << 4))) = f2bf(h);
                }
        }
    }
    __syncthreads();

    // ================= DENSITY: GEMM2 (K=128) + W3 dot =================
    {
        f32x4 acc[4][2];
#pragma unroll
        for (int mt = 0; mt < 4; ++mt)
#pragma unroll
            for (int nl = 0; nl < 2; ++nl) acc[mt][nl] = FZ;
#pragma unroll
        for (int kk = 0; kk < 4; ++kk) {
            bf16x8 a[4];
#pragma unroll
            for (int mt = 0; mt < 4; ++mt) {
                const int m = wr * 64 + mt * 16 + l15;
                a[mt] = *(const bf16x8*)((const char*)sH + m * 256 + ((kk * 64 + kb) ^ ((m & 7) << 4)));
            }
#pragma unroll
            for (int nl = 0; nl < 2; ++nl) {
                const int n = wc * 32 + nl * 16 + l15;
                const bf16x8 b = *(const bf16x8*)(gW2d + n * 128 + kk * 32 + l4 * 8);
#pragma unroll
                for (int mt = 0; mt < 4; ++mt)
                    acc[mt][nl] = __builtin_amdgcn_mfma_f32_16x16x32_bf16(a[mt], b, acc[mt][nl], 0, 0, 0);
            }
        }
#pragma unroll
        for (int mt = 0; mt < 4; ++mt)
#pragma unroll
            for (int r = 0; r < 4; ++r) {
                float s = 0.f;
#pragma unroll
                for (int nl = 0; nl < 2; ++nl) {
                    const int n = wc * 32 + nl * 16 + l15;
                    float h = acc[mt][nl][r] + gB2d[n];
                    h = h > 0.f ? h : 0.f;
                    s += h * gW3d[n];
                }
                s += __shfl_xor(s, 1);
                s += __shfl_xor(s, 2);
                s += __shfl_xor(s, 4);
                s += __shfl_xor(s, 8);
                if (l15 == 0)
                    atomicAdd(&sAcc[0 * 128 + wr * 64 + mt * 16 + l4 * 4 + r], s);
            }
    }
    __syncthreads();   // also guards sH overwrite below

    // ================= COLOR: GEMM1 (K=64) =================
    {
        f32x4 acc[4][2];
#pragma unroll
        for (int mt = 0; mt < 4; ++mt)
#pragma unroll
            for (int nl = 0; nl < 2; ++nl) acc[mt][nl] = FZ;
#pragma unroll
        for (int kk = 0; kk < 2; ++kk) {
            bf16x8 a[4];
#pragma unroll
            for (int mt = 0; mt < 4; ++mt) {
                const int m = wr * 64 + mt * 16 + l15;
                a[mt] = *(const bf16x8*)((const char*)sX + m * 128 + ((kk * 64 + kb) ^ ((m & 7) << 4)));
            }
#pragma unroll
            for (int nl = 0; nl < 2; ++nl) {
                const int n = wc * 32 + nl * 16 + l15;
                const bf16x8 b = *(const bf16x8*)(gW1c + n * 64 + kk * 32 + l4 * 8);
#pragma unroll
                for (int mt = 0; mt < 4; ++mt)
                    acc[mt][nl] = __builtin_amdgcn_mfma_f32_16x16x32_bf16(a[mt], b, acc[mt][nl], 0, 0, 0);
            }
        }
#pragma unroll
        for (int nl = 0; nl < 2; ++nl) {
            const int n = wc * 32 + nl * 16 + l15;
            const float bias = gB1c[n];
#pragma unroll
            for (int mt = 0; mt < 4; ++mt)
#pragma unroll
                for (int r = 0; r < 4; ++r) {
                    const int m = wr * 64 + mt * 16 + l4 * 4 + r;
                    float h = acc[mt][nl][r] + bias;
                    h = h > 0.f ? h : 0.f;
                    *(u16*)((char*)sH + m * 256 + ((n * 2) ^ ((m & 7) << 4))) = f2bf(h);
                }
        }
    }
    __syncthreads();

    // ================= COLOR: GEMM2 (K=128) + W3 dots =================
    {
        f32x4 acc[4][2];
#pragma unroll
        for (int mt = 0; mt < 4; ++mt)
#pragma unroll
            for (int nl = 0; nl < 2; ++nl) acc[mt][nl] = FZ;
#pragma unroll
        for (int kk = 0; kk < 4; ++kk) {
            bf16x8 a[4];
#pragma unroll
            for (int mt = 0; mt < 4; ++mt) {
                const int m = wr * 64 + mt * 16 + l15;
                a[mt] = *(const bf16x8*)((const char*)sH + m * 256 + ((kk * 64 + kb) ^ ((m & 7) << 4)));
            }
#pragma unroll
            for (int nl = 0; nl < 2; ++nl) {
                const int n = wc * 32 + nl * 16 + l15;
                const bf16x8 b = *(const bf16x8*)(gW2c + n * 128 + kk * 32 + l4 * 8);
#pragma unroll
                for (int mt = 0; mt < 4; ++mt)
                    acc[mt][nl] = __builtin_amdgcn_mfma_f32_16x16x32_bf16(a[mt], b, acc[mt][nl], 0, 0, 0);
            }
        }
#pragma unroll
        for (int mt = 0; mt < 4; ++mt)
#pragma unroll
            for (int r = 0; r < 4; ++r) {
                float s0 = 0.f, s1 = 0.f, s2 = 0.f;
#pragma unroll
                for (int nl = 0; nl < 2; ++nl) {
                    const int n = wc * 32 + nl * 16 + l15;
                    float h = acc[mt][nl][r] + gB2c[n];
                    h = h > 0.f ? h : 0.f;
                    s0 += h * gW3c[n * 3 + 0];
                    s1 += h * gW3c[n * 3 + 1];
                    s2 += h * gW3c[n * 3 + 2];
                }
                s0 += __shfl_xor(s0, 1); s0 += __shfl_xor(s0, 2); s0 += __shfl_xor(s0, 4); s0 += __shfl_xor(s0, 8);
                s1 += __shfl_xor(s1, 1); s1 += __shfl_xor(s1, 2); s1 += __shfl_xor(s1, 4); s1 += __shfl_xor(s1, 8);
                s2 += __shfl_xor(s2, 1); s2 += __shfl_xor(s2, 2); s2 += __shfl_xor(s2, 4); s2 += __shfl_xor(s2, 8);
                if (l15 == 0) {
                    const int m = wr * 64 + mt * 16 + l4 * 4 + r;
                    atomicAdd(&sAcc[1 * 128 + m], s0);
                    atomicAdd(&sAcc[2 * 128 + m], s1);
                    atomicAdd(&sAcc[3 * 128 + m], s2);
                }
            }
    }
    __syncthreads();

    // ---- write out (1,4,N): ch0 = density, ch1..3 = color ----
    {
        const int ch = t >> 7, row = t & 127;
        const float bias = (ch == 0) ? gB3d[0] : gB3c[ch - 1];
        out[(size_t)ch * NPTS + pbase + row] = sAcc[ch * 128 + row] + bias;
    }
}

// ---------------------------------------------------------------------------
extern "C" void kernel_launch(void* const* d_in, const int* in_sizes, int n_in,
                              void* d_out, int out_size, void* d_ws, size_t ws_size,
                              hipStream_t stream) {
    (void)in_sizes; (void)n_in; (void)out_size; (void)ws_size;
    const float* pts = (const float*)d_in[0];
    const float* vds = (const float*)d_in[1];
    const float* tp  = (const float*)d_in[2];
    const float* dW1 = (const float*)d_in[3];
    const float* dB1 = (const float*)d_in[4];
    const float* dW2 = (const float*)d_in[5];
    const float* dB2 = (const float*)d_in[6];
    const float* dW3 = (const float*)d_in[7];
    const float* dB3 = (const float*)d_in[8];
    const float* cW1 = (const float*)d_in[9];
    const float* cB1 = (const float*)d_in[10];
    const float* cW2 = (const float*)d_in[11];
    const float* cB2 = (const float*)d_in[12];
    const float* cW3 = (const float*)d_in[13];
    const float* cB3 = (const float*)d_in[14];
    float* out = (float*)d_out;

    u16* planes_t = (u16*)d_ws;                          // 3*256*256*32 bf16 = 12 MB
    u16* w1d = planes_t + (size_t)3 * RES * RES * PD;
    u16* w1c = w1d + 128 * 32;
    u16* w2d = w1c + 128 * 64;
    u16* w2c = w2d + 128 * 128;

    k_transpose_planes<<<3 * RES, 256, 0, stream>>>(tp, planes_t);
    k_prep_weights<<<64, 256, 0, stream>>>(dW1, dW2, cW1, cW2, w1d, w1c, w2d, w2c);
    k_fused<<<NPTS / 128, 512, 0, stream>>>(pts, vds, planes_t,
                                            w1d, w1c, w2d, w2c,
                                            dB1, dB2, dW3, dB3,
                                            cB1, cB2, cW3, cB3,
                                            out);
}

// Round 3
// 136.360 us; speedup vs baseline: 1.2774x; 1.2258x over previous
//
#include <hip/hip_runtime.h>

#define NPTS 262144
#define RES  256
#define PD   32

typedef unsigned short u16;
typedef unsigned int   u32;

typedef __bf16 bf16x8 __attribute__((ext_vector_type(8)));
typedef float  f32x4  __attribute__((ext_vector_type(4)));

__device__ __forceinline__ u16 f2bf(float f) {
    return __builtin_bit_cast(u16, (__bf16)f);
}
__device__ __forceinline__ float bf2f(u32 u) {
    return __builtin_bit_cast(float, (u32)(u << 16));
}

// ---------------------------------------------------------------------------
// Prep 1: triplanes (3,32,256,256) fp32 -> (3,256,256,32) bf16
// ---------------------------------------------------------------------------
__global__ void k_transpose_planes(const float* __restrict__ tp, u16* __restrict__ dst) {
    const int b  = blockIdx.x;          // 0..767
    const int pl = b >> 8, y = b & 255;
    const int x  = threadIdx.x;         // 0..255
    const float* src = tp + ((size_t)pl * PD * RES + y) * RES + x;
    u32 w[16];
#pragma unroll
    for (int c = 0; c < 16; ++c) {
        const float v0 = src[(size_t)(2 * c)     * (RES * RES)];
        const float v1 = src[(size_t)(2 * c + 1) * (RES * RES)];
        w[c] = (u32)f2bf(v0) | ((u32)f2bf(v1) << 16);
    }
    uint4* d = (uint4*)(dst + (size_t)((pl * RES + y) * RES + x) * PD);
    d[0] = make_uint4(w[0],  w[1],  w[2],  w[3]);
    d[1] = make_uint4(w[4],  w[5],  w[6],  w[7]);
    d[2] = make_uint4(w[8],  w[9],  w[10], w[11]);
    d[3] = make_uint4(w[12], w[13], w[14], w[15]);
}

// ---------------------------------------------------------------------------
// Prep 2: weights -> bf16, transposed to (N x K) row-major.
// ---------------------------------------------------------------------------
__global__ void k_prep_weights(const float* __restrict__ dW1, const float* __restrict__ dW2,
                               const float* __restrict__ cW1, const float* __restrict__ cW2,
                               u16* __restrict__ w1d, u16* __restrict__ w1c,
                               u16* __restrict__ w2d, u16* __restrict__ w2c) {
    const int tid = blockIdx.x * 256 + threadIdx.x;   // 0..16383
    if (tid < 128 * 32) { const int n = tid >> 5, k = tid & 31; w1d[tid] = f2bf(dW1[k * 128 + n]); }
    if (tid < 128 * 64) { const int n = tid >> 6, k = tid & 63; w1c[tid] = f2bf(k < 59 ? cW1[k * 128 + n] : 0.f); }
    { const int n = tid >> 7, k = tid & 127;
      w2d[tid] = f2bf(dW2[k * 128 + n]);
      w2c[tid] = f2bf(cW2[k * 128 + n]); }
}

// ---------------------------------------------------------------------------
// Fused head kernel. 2048 blocks x 512 threads, TILE = 128 points/block.
// LDS = 50 KB -> 3 blocks/CU; weights read directly from global (L2-hot).
// __launch_bounds__(512,2): proven no-spill config (88 VGPR in round 1).
// ---------------------------------------------------------------------------
__global__ __launch_bounds__(512, 2) void k_fused(
    const float* __restrict__ pts, const float* __restrict__ vds,
    const u16* __restrict__ planes,
    const u16* __restrict__ gW1d, const u16* __restrict__ gW1c,
    const u16* __restrict__ gW2d, const u16* __restrict__ gW2c,
    const float* __restrict__ gB1d, const float* __restrict__ gB2d,
    const float* __restrict__ gW3d, const float* __restrict__ gB3d,
    const float* __restrict__ gB1c, const float* __restrict__ gB2c,
    const float* __restrict__ gW3c, const float* __restrict__ gB3c,
    float* __restrict__ out) {
    __shared__ __align__(16) u16 sX[128 * 64];      // 16 KB, 128B rows, XOR-swizzled
    __shared__ __align__(16) u16 sH[128 * 128];     // 32 KB, 256B rows, XOR-swizzled
    __shared__ float sAcc[4 * 128];                 //  2 KB

    const int t    = threadIdx.x;
    const int lane = t & 63;
    const int wid  = t >> 6;
    const int l15  = lane & 15;
    const int l4   = lane >> 4;
    const int pbase = blockIdx.x * 128;

    sAcc[t & 511] = 0.f;   // 512 threads cover all 512 slots

    // ---- phase 1: bilinear triplane sampling + view embedding -> sX ----
    {
        const int p = t >> 2, q = t & 3;       // 4 threads/point, q = 8-channel slice
        const int pg = pbase + p;
        const int sw = (p & 7) << 4;
        const float pu = pts[pg], pv = pts[NPTS + pg], pw = pts[2 * NPTS + pg];
        float facc[8] = {0.f, 0.f, 0.f, 0.f, 0.f, 0.f, 0.f, 0.f};
#pragma unroll
        for (int pl = 0; pl < 3; ++pl) {
            const float gx = (pl == 0) ? pv : pu;
            const float gy = (pl == 2) ? pv : pw;
            const float px = (gx + 1.f) * 127.5f;
            const float py = (gy + 1.f) * 127.5f;
            const float x0 = floorf(px), y0 = floorf(py);
            const float fx = px - x0, fy = py - y0;
            const int ix = (int)x0, iy = (int)y0;
            const u16* pb = planes + (size_t)pl * (RES * RES * PD) + q * 8;
#pragma unroll
            for (int dy = 0; dy < 2; ++dy) {
#pragma unroll
                for (int dx = 0; dx < 2; ++dx) {
                    const int xi = ix + dx, yi = iy + dy;
                    float wt = (dx ? fx : 1.f - fx) * (dy ? fy : 1.f - fy);
                    if (xi < 0 || xi > RES - 1 || yi < 0 || yi > RES - 1) wt = 0.f;
                    const int xc = xi < 0 ? 0 : (xi > RES - 1 ? RES - 1 : xi);
                    const int yc = yi < 0 ? 0 : (yi > RES - 1 ? RES - 1 : yi);
                    const uint4 v = *(const uint4*)(pb + ((size_t)(yc * RES + xc) << 5));
                    facc[0] += wt * bf2f(v.x & 0xffffu);
                    facc[1] += wt * bf2f(v.x >> 16);
                    facc[2] += wt * bf2f(v.y & 0xffffu);
                    facc[3] += wt * bf2f(v.y >> 16);
                    facc[4] += wt * bf2f(v.z & 0xffffu);
                    facc[5] += wt * bf2f(v.z >> 16);
                    facc[6] += wt * bf2f(v.w & 0xffffu);
                    facc[7] += wt * bf2f(v.w >> 16);
                }
            }
        }
        {
            u32 wp[4];
#pragma unroll
            for (int i = 0; i < 4; ++i)
                wp[i] = (u32)f2bf(facc[2 * i]) | ((u32)f2bf(facc[2 * i + 1]) << 16);
            *(uint4*)((char*)sX + p * 128 + ((q * 16) ^ sw)) =
                make_uint4(wp[0], wp[1], wp[2], wp[3]);
        }

        // view embedding -> X cols 32..63 (59..63 zero): q==1 does [d|sin|cos(d0)],
        // q==2 does the remaining cos + pad.
        if (q == 1 || q == 2) {
            const float d0 = vds[pg], d1 = vds[NPTS + pg], d2 = vds[2 * NPTS + pg];
            float e[16];
            if (q == 1) {
                e[0] = d0; e[1] = d1; e[2] = d2;
#pragma unroll
                for (int f = 0; f < 4; ++f) {
                    const float fr = (float)(1 << f);
                    e[3 + f * 3 + 0] = __sinf(d0 * fr);
                    e[3 + f * 3 + 1] = __sinf(d1 * fr);
                    e[3 + f * 3 + 2] = __sinf(d2 * fr);
                }
                e[15] = __cosf(d0);
            } else {
                e[0] = __cosf(d1); e[1] = __cosf(d2);
#pragma unroll
                for (int f = 1; f < 4; ++f) {
                    const float fr = (float)(1 << f);
                    e[2 + (f - 1) * 3 + 0] = __cosf(d0 * fr);
                    e[2 + (f - 1) * 3 + 1] = __cosf(d1 * fr);
                    e[2 + (f - 1) * 3 + 2] = __cosf(d2 * fr);
                }
#pragma unroll
                for (int i = 11; i < 16; ++i) e[i] = 0.f;
            }
            const int base = 64 + (q - 1) * 32;
#pragma unroll
            for (int g = 0; g < 2; ++g) {
                const u32 a0 = (u32)f2bf(e[8 * g + 0]) | ((u32)f2bf(e[8 * g + 1]) << 16);
                const u32 a1 = (u32)f2bf(e[8 * g + 2]) | ((u32)f2bf(e[8 * g + 3]) << 16);
                const u32 a2 = (u32)f2bf(e[8 * g + 4]) | ((u32)f2bf(e[8 * g + 5]) << 16);
                const u32 a3 = (u32)f2bf(e[8 * g + 6]) | ((u32)f2bf(e[8 * g + 7]) << 16);
                *(uint4*)((char*)sX + p * 128 + ((base + g * 16) ^ sw)) =
                    make_uint4(a0, a1, a2, a3);
            }
        }
    }
    __syncthreads();

    // ---- GEMM phase: wave grid 2 (M) x 4 (N); wave owns 64 rows x 32 cols ----
    const int wr = wid >> 2;        // 0..1
    const int wc = wid & 3;         // 0..3
    const int kb = l4 * 16;         // byte offset of lane's k-slice in a 64B k-step
    const f32x4 FZ = {0.f, 0.f, 0.f, 0.f};

    // ================= DENSITY: GEMM1 (K=32) =================
    {
        f32x4 acc[4][2];
        bf16x8 a[4];
#pragma unroll
        for (int mt = 0; mt < 4; ++mt) {
            const int m = wr * 64 + mt * 16 + l15;
            a[mt] = *(const bf16x8*)((const char*)sX + m * 128 + (kb ^ ((m & 7) << 4)));
#pragma unroll
            for (int nl = 0; nl < 2; ++nl) acc[mt][nl] = FZ;
        }
#pragma unroll
        for (int nl = 0; nl < 2; ++nl) {
            const int n = wc * 32 + nl * 16 + l15;
            const bf16x8 b = *(const bf16x8*)(gW1d + n * 32 + l4 * 8);
#pragma unroll
            for (int mt = 0; mt < 4; ++mt)
                acc[mt][nl] = __builtin_amdgcn_mfma_f32_16x16x32_bf16(a[mt], b, acc[mt][nl], 0, 0, 0);
        }
#pragma unroll
        for (int nl = 0; nl < 2; ++nl) {
            const int n = wc * 32 + nl * 16 + l15;
            const float bias = gB1d[n];
#pragma unroll
            for (int mt = 0; mt < 4; ++mt)
#pragma unroll
                for (int r = 0; r < 4; ++r) {
                    const int m = wr * 64 + mt * 16 + l4 * 4 + r;
                    float h = acc[mt][nl][r] + bias;
                    h = h > 0.f ? h : 0.f;
                    *(u16*)((char*)sH + m * 256 + ((n * 2) ^ ((m & 7) << 4))) = f2bf(h);
                }
        }
    }
    __syncthreads();

    // ================= DENSITY: GEMM2 (K=128) + W3 dot =================
    {
        f32x4 acc[4][2];
#pragma unroll
        for (int mt = 0; mt < 4; ++mt)
#pragma unroll
            for (int nl = 0; nl < 2; ++nl) acc[mt][nl] = FZ;
#pragma unroll
        for (int kk = 0; kk < 4; ++kk) {
            bf16x8 a[4];
#pragma unroll
            for (int mt = 0; mt < 4; ++mt) {
                const int m = wr * 64 + mt * 16 + l15;
                a[mt] = *(const bf16x8*)((const char*)sH + m * 256 + ((kk * 64 + kb) ^ ((m & 7) << 4)));
            }
#pragma unroll
            for (int nl = 0; nl < 2; ++nl) {
                const int n = wc * 32 + nl * 16 + l15;
                const bf16x8 b = *(const bf16x8*)(gW2d + n * 128 + kk * 32 + l4 * 8);
#pragma unroll
                for (int mt = 0; mt < 4; ++mt)
                    acc[mt][nl] = __builtin_amdgcn_mfma_f32_16x16x32_bf16(a[mt], b, acc[mt][nl], 0, 0, 0);
            }
        }
#pragma unroll
        for (int mt = 0; mt < 4; ++mt)
#pragma unroll
            for (int r = 0; r < 4; ++r) {
                float s = 0.f;
#pragma unroll
                for (int nl = 0; nl < 2; ++nl) {
                    const int n = wc * 32 + nl * 16 + l15;
                    float h = acc[mt][nl][r] + gB2d[n];
                    h = h > 0.f ? h : 0.f;
                    s += h * gW3d[n];
                }
                s += __shfl_xor(s, 1);
                s += __shfl_xor(s, 2);
                s += __shfl_xor(s, 4);
                s += __shfl_xor(s, 8);
                if (l15 == 0)
                    atomicAdd(&sAcc[0 * 128 + wr * 64 + mt * 16 + l4 * 4 + r], s);
            }
    }
    __syncthreads();   // also guards sH overwrite below

    // ================= COLOR: GEMM1 (K=64) =================
    {
        f32x4 acc[4][2];
#pragma unroll
        for (int mt = 0; mt < 4; ++mt)
#pragma unroll
            for (int nl = 0; nl < 2; ++nl) acc[mt][nl] = FZ;
#pragma unroll
        for (int kk = 0; kk < 2; ++kk) {
            bf16x8 a[4];
#pragma unroll
            for (int mt = 0; mt < 4; ++mt) {
                const int m = wr * 64 + mt * 16 + l15;
                a[mt] = *(const bf16x8*)((const char*)sX + m * 128 + ((kk * 64 + kb) ^ ((m & 7) << 4)));
            }
#pragma unroll
            for (int nl = 0; nl < 2; ++nl) {
                const int n = wc * 32 + nl * 16 + l15;
                const bf16x8 b = *(const bf16x8*)(gW1c + n * 64 + kk * 32 + l4 * 8);
#pragma unroll
                for (int mt = 0; mt < 4; ++mt)
                    acc[mt][nl] = __builtin_amdgcn_mfma_f32_16x16x32_bf16(a[mt], b, acc[mt][nl], 0, 0, 0);
            }
        }
#pragma unroll
        for (int nl = 0; nl < 2; ++nl) {
            const int n = wc * 32 + nl * 16 + l15;
            const float bias = gB1c[n];
#pragma unroll
            for (int mt = 0; mt < 4; ++mt)
#pragma unroll
                for (int r = 0; r < 4; ++r) {
                    const int m = wr * 64 + mt * 16 + l4 * 4 + r;
                    float h = acc[mt][nl][r] + bias;
                    h = h > 0.f ? h : 0.f;
                    *(u16*)((char*)sH + m * 256 + ((n * 2) ^ ((m & 7) << 4))) = f2bf(h);
                }
        }
    }
    __syncthreads();

    // ================= COLOR: GEMM2 (K=128) + W3 dots =================
    {
        f32x4 acc[4][2];
#pragma unroll
        for (int mt = 0; mt < 4; ++mt)
#pragma unroll
            for (int nl = 0; nl < 2; ++nl) acc[mt][nl] = FZ;
#pragma unroll
        for (int kk = 0; kk < 4; ++kk) {
            bf16x8 a[4];
#pragma unroll
            for (int mt = 0; mt < 4; ++mt) {
                const int m = wr * 64 + mt * 16 + l15;
                a[mt] = *(const bf16x8*)((const char*)sH + m * 256 + ((kk * 64 + kb) ^ ((m & 7) << 4)));
            }
#pragma unroll
            for (int nl = 0; nl < 2; ++nl) {
                const int n = wc * 32 + nl * 16 + l15;
                const bf16x8 b = *(const bf16x8*)(gW2c + n * 128 + kk * 32 + l4 * 8);
#pragma unroll
                for (int mt = 0; mt < 4; ++mt)
                    acc[mt][nl] = __builtin_amdgcn_mfma_f32_16x16x32_bf16(a[mt], b, acc[mt][nl], 0, 0, 0);
            }
        }
#pragma unroll
        for (int mt = 0; mt < 4; ++mt)
#pragma unroll
            for (int r = 0; r < 4; ++r) {
                float s0 = 0.f, s1 = 0.f, s2 = 0.f;
#pragma unroll
                for (int nl = 0; nl < 2; ++nl) {
                    const int n = wc * 32 + nl * 16 + l15;
                    float h = acc[mt][nl][r] + gB2c[n];
                    h = h > 0.f ? h : 0.f;
                    s0 += h * gW3c[n * 3 + 0];
                    s1 += h * gW3c[n * 3 + 1];
                    s2 += h * gW3c[n * 3 + 2];
                }
                s0 += __shfl_xor(s0, 1); s0 += __shfl_xor(s0, 2); s0 += __shfl_xor(s0, 4); s0 += __shfl_xor(s0, 8);
                s1 += __shfl_xor(s1, 1); s1 += __shfl_xor(s1, 2); s1 += __shfl_xor(s1, 4); s1 += __shfl_xor(s1, 8);
                s2 += __shfl_xor(s2, 1); s2 += __shfl_xor(s2, 2); s2 += __shfl_xor(s2, 4); s2 += __shfl_xor(s2, 8);
                if (l15 == 0) {
                    const int m = wr * 64 + mt * 16 + l4 * 4 + r;
                    atomicAdd(&sAcc[1 * 128 + m], s0);
                    atomicAdd(&sAcc[2 * 128 + m], s1);
                    atomicAdd(&sAcc[3 * 128 + m], s2);
                }
            }
    }
    __syncthreads();

    // ---- write out (1,4,N): ch0 = density, ch1..3 = color ----
    {
        const int ch = t >> 7, row = t & 127;
        const float bias = (ch == 0) ? gB3d[0] : gB3c[ch - 1];
        out[(size_t)ch * NPTS + pbase + row] = sAcc[ch * 128 + row] + bias;
    }
}

// ---------------------------------------------------------------------------
extern "C" void kernel_launch(void* const* d_in, const int* in_sizes, int n_in,
                              void* d_out, int out_size, void* d_ws, size_t ws_size,
                              hipStream_t stream) {
    (void)in_sizes; (void)n_in; (void)out_size; (void)ws_size;
    const float* pts = (const float*)d_in[0];
    const float* vds = (const float*)d_in[1];
    const float* tp  = (const float*)d_in[2];
    const float* dW1 = (const float*)d_in[3];
    const float* dB1 = (const float*)d_in[4];
    const float* dW2 = (const float*)d_in[5];
    const float* dB2 = (const float*)d_in[6];
    const float* dW3 = (const float*)d_in[7];
    const float* dB3 = (const float*)d_in[8];
    const float* cW1 = (const float*)d_in[9];
    const float* cB1 = (const float*)d_in[10];
    const float* cW2 = (const float*)d_in[11];
    const float* cB2 = (const float*)d_in[12];
    const float* cW3 = (const float*)d_in[13];
    const float* cB3 = (const float*)d_in[14];
    float* out = (float*)d_out;

    u16* planes_t = (u16*)d_ws;                          // 3*256*256*32 bf16 = 12 MB
    u16* w1d = planes_t + (size_t)3 * RES * RES * PD;
    u16* w1c = w1d + 128 * 32;
    u16* w2d = w1c + 128 * 64;
    u16* w2c = w2d + 128 * 128;

    k_transpose_planes<<<3 * RES, 256, 0, stream>>>(tp, planes_t);
    k_prep_weights<<<64, 256, 0, stream>>>(dW1, dW2, cW1, cW2, w1d, w1c, w2d, w2c);
    k_fused<<<NPTS / 128, 512, 0, stream>>>(pts, vds, planes_t,
                                            w1d, w1c, w2d, w2c,
                                            dB1, dB2, dW3, dB3,
                                            cB1, cB2, cW3, cB3,
                                            out);
}